// Round 1
// baseline (117.021 us; speedup 1.0000x reference)
//
#include <hip/hip_runtime.h>
#include <math.h>

// FC-CapsNet routing: u[128,1152,8], W[1152,32,8,16], b[1152,32] -> v[128,32,16]
//
// Kernel 1 (caps_main): grid (64 i-chunks, 4 b-groups), block 512 = 8 waves.
//   Each wave owns 4 batches (register-blocked) for all (j,m); W[i] staged in
//   LDS (double-buffered, XOR-swizzled) and shared by all 32 batches of the
//   block. Softmax over j via wave shuffles. Writes per-(b,chunk) partial s.
// Kernel 2 (caps_fin): reduces 64 chunk-partials, applies squash.

#define NB 128
#define NI 1152
#define DN 8
#define NJ 32
#define DM 16
#define JMSZ 512            // NJ*DM
#define TPB 512
#define NWAVE 8
#define BB 4                // batches per wave (register blocking)
#define BPB (NWAVE * BB)    // 32 batches per block
#define NBG (NB / BPB)      // 4 batch groups
#define NCHUNK 64
#define IC (NI / NCHUNK)    // 18 i per chunk

// LDS layout: W[i] as [j][n][m] floats (4096 f32 = 16KB), XOR-swizzled:
// byte ^= ((row&7)<<4) where row = byte>>9 (= j). Spreads the j-stride-512B
// column reads across banks (G4 pattern); within a 16-lane quarter the 16
// distinct 16B slots cover each bank-quad exactly 2x (minimum for b128).
__device__ __forceinline__ float4 ldsW(const float* base, int j, int byteInRow) {
  int byte = (j << 9) + byteInRow;
  byte ^= ((j & 7) << 4);
  return *(const float4*)((const char*)base + byte);
}

__device__ __forceinline__ void stageW(float* dst, const float* src, int tid) {
#pragma unroll
  for (int q = 0; q < 2; ++q) {
    int o = (tid + q * TPB) << 4;              // byte offset 0..16383
    int so = o ^ (((o >> 9) & 7) << 4);        // same involution as reader
    *(float4*)((char*)dst + so) = *(const float4*)((const char*)src + o);
  }
}

template <bool ATOMIC>
__global__ __launch_bounds__(TPB, 4) void caps_main(
    const float* __restrict__ u, const float* __restrict__ W,
    const float* __restrict__ bias, float* __restrict__ out) {
  __shared__ __align__(16) float wl[2][4096];

  const int chunk = blockIdx.x;                // 0..NCHUNK-1
  const int bg = blockIdx.y;                   // 0..NBG-1
  const int tid = threadIdx.x;
  const int wid = tid >> 6;                    // wave id 0..7
  const int lane = tid & 63;
  const int j = lane >> 1;                     // parent capsule 0..31
  const int h = lane & 1;                      // m-octet: m = 8h..8h+7
  // readfirstlane: make b0 provably wave-uniform so u loads scalarize (SGPRs)
  const int b0 = __builtin_amdgcn_readfirstlane(bg * BPB + wid * BB);
  const int i0 = chunk * IC;

  stageW(wl[0], W + (size_t)i0 * 4096, tid);

  float acc[BB][8];
#pragma unroll
  for (int bb = 0; bb < BB; ++bb)
#pragma unroll
    for (int k = 0; k < 8; ++k) acc[bb][k] = 0.f;

  for (int t = 0; t < IC; ++t) {
    const int i = i0 + t;
    __syncthreads();  // buf[t&1] staged; everyone done reading buf[(t+1)&1]
    if (t + 1 < IC) stageW(wl[(t + 1) & 1], W + (size_t)(i + 1) * 4096, tid);
    const float* wb = wl[t & 1];

    // u[b0+bb, i, 0..7] — wave-uniform addresses -> scalar loads
    float un[BB][8];
#pragma unroll
    for (int bb = 0; bb < BB; ++bb) {
      const float* up = u + ((size_t)(b0 + bb) * NI + i) * DN;
      float4 a0 = *(const float4*)up;
      float4 a1 = *(const float4*)(up + 4);
      un[bb][0] = a0.x; un[bb][1] = a0.y; un[bb][2] = a0.z; un[bb][3] = a0.w;
      un[bb][4] = a1.x; un[bb][5] = a1.y; un[bb][6] = a1.z; un[bb][7] = a1.w;
    }
    const float bj = bias[(size_t)i * NJ + j];

    // u_hat[bb][m-octet]: 8 outputs per lane per batch
    float uh[BB][8];
#pragma unroll
    for (int bb = 0; bb < BB; ++bb)
#pragma unroll
      for (int k = 0; k < 8; ++k) uh[bb][k] = 0.f;

#pragma unroll
    for (int n = 0; n < 8; ++n) {
      const int rb = n * 64 + h * 32;
      float4 w0 = ldsW(wb, j, rb);
      float4 w1 = ldsW(wb, j, rb + 16);
#pragma unroll
      for (int bb = 0; bb < BB; ++bb) {
        const float uv = un[bb][n];
        uh[bb][0] = fmaf(uv, w0.x, uh[bb][0]);
        uh[bb][1] = fmaf(uv, w0.y, uh[bb][1]);
        uh[bb][2] = fmaf(uv, w0.z, uh[bb][2]);
        uh[bb][3] = fmaf(uv, w0.w, uh[bb][3]);
        uh[bb][4] = fmaf(uv, w1.x, uh[bb][4]);
        uh[bb][5] = fmaf(uv, w1.y, uh[bb][5]);
        uh[bb][6] = fmaf(uv, w1.z, uh[bb][6]);
        uh[bb][7] = fmaf(uv, w1.w, uh[bb][7]);
      }
    }

    // agreement + softmax over j (32) + bias, then accumulate s
#pragma unroll
    for (int bb = 0; bb < BB; ++bb) {
      float s2 = uh[bb][0] * uh[bb][0] + uh[bb][1] * uh[bb][1] +
                 uh[bb][2] * uh[bb][2] + uh[bb][3] * uh[bb][3] +
                 uh[bb][4] * uh[bb][4] + uh[bb][5] * uh[bb][5] +
                 uh[bb][6] * uh[bb][6] + uh[bb][7] * uh[bb][7];
      s2 += __shfl_xor(s2, 1);                 // combine the two m-octets
      const float a = s2 * 0.25f;              // / sqrt(16)
      float mx = a;
      mx = fmaxf(mx, __shfl_xor(mx, 2));
      mx = fmaxf(mx, __shfl_xor(mx, 4));
      mx = fmaxf(mx, __shfl_xor(mx, 8));
      mx = fmaxf(mx, __shfl_xor(mx, 16));
      mx = fmaxf(mx, __shfl_xor(mx, 32));      // max over all 32 j
      const float e = __expf(a - mx);
      float es = e;
      es += __shfl_xor(es, 2);
      es += __shfl_xor(es, 4);
      es += __shfl_xor(es, 8);
      es += __shfl_xor(es, 16);
      es += __shfl_xor(es, 32);                // sum over all 32 j (h-closed)
      const float c = e * __builtin_amdgcn_rcpf(es) + bj;
#pragma unroll
      for (int k = 0; k < 8; ++k) acc[bb][k] = fmaf(c, uh[bb][k], acc[bb][k]);
    }
  }

#pragma unroll
  for (int bb = 0; bb < BB; ++bb) {
    if (ATOMIC) {
      float* p = out + (size_t)(b0 + bb) * JMSZ + j * DM + h * 8;
#pragma unroll
      for (int k = 0; k < 8; ++k) atomicAdd(p + k, acc[bb][k]);
    } else {
      float* p = out + ((size_t)(b0 + bb) * NCHUNK + chunk) * JMSZ + j * DM + h * 8;
      *(float4*)p = make_float4(acc[bb][0], acc[bb][1], acc[bb][2], acc[bb][3]);
      *(float4*)(p + 4) = make_float4(acc[bb][4], acc[bb][5], acc[bb][6], acc[bb][7]);
    }
  }
}

// Reduce chunk partials (NSUM>1) or read accumulated s (NSUM==1); squash.
template <int NSUM>
__global__ __launch_bounds__(256) void caps_fin(const float* __restrict__ part,
                                               float* __restrict__ v) {
  const int tid = blockIdx.x * 256 + threadIdx.x;  // = b*512 + j*16 + m
  float s = 0.f;
  if (NSUM > 1) {
    const int b = tid >> 9;
    const int jm = tid & 511;
    const float* p = part + (size_t)b * NSUM * JMSZ + jm;
#pragma unroll 8
    for (int c = 0; c < NSUM; ++c) s += p[(size_t)c * JMSZ];
  } else {
    s = part[tid];
  }
  // norm over m: 16 consecutive lanes share (b,j)
  float sq = s * s;
  sq += __shfl_xor(sq, 1);
  sq += __shfl_xor(sq, 2);
  sq += __shfl_xor(sq, 4);
  sq += __shfl_xor(sq, 8);
  const float nrm = sqrtf(sq);
  const float f = (sq / (1.0f + sq)) / (nrm + 1e-20f);
  v[tid] = f * s;
}

extern "C" void kernel_launch(void* const* d_in, const int* in_sizes, int n_in,
                              void* d_out, int out_size, void* d_ws, size_t ws_size,
                              hipStream_t stream) {
  const float* u = (const float*)d_in[0];
  const float* W = (const float*)d_in[1];
  const float* bias = (const float*)d_in[2];
  float* out = (float*)d_out;

  const size_t part_bytes = (size_t)NB * NCHUNK * JMSZ * sizeof(float);  // 16 MB
  dim3 grid(NCHUNK, NBG);

  if (ws_size >= part_bytes) {
    float* part = (float*)d_ws;
    caps_main<false><<<grid, TPB, 0, stream>>>(u, W, bias, part);
    caps_fin<NCHUNK><<<(NB * JMSZ) / 256, 256, 0, stream>>>(part, out);
  } else {
    // fallback: atomic accumulation into 256KB s buffer
    float* sbuf = (float*)d_ws;
    hipMemsetAsync(sbuf, 0, (size_t)NB * JMSZ * sizeof(float), stream);
    caps_main<true><<<grid, TPB, 0, stream>>>(u, W, bias, sbuf);
    caps_fin<1><<<(NB * JMSZ) / 256, 256, 0, stream>>>(sbuf, out);
  }
}

// Round 3
// 104.534 us; speedup vs baseline: 1.1195x; 1.1195x over previous
//
#include <hip/hip_runtime.h>
#include <math.h>

// FC-CapsNet routing: u[128,1152,8], W[1152,32,8,16], b[1152,32] -> v[128,32,16]
// R3: revert cross-lane to proven __shfl_xor (R2's DPP/permlane chain failed
// correctness on HW); keep max-free softmax (6 shuffles, was 11), 4x occupancy
// (1024 blocks of 256), and parallelized reduce+squash kernel.

#define NB 128
#define NI 1152
#define NJ 32
#define DM 16
#define JMSZ 512            // NJ*DM
#define BB 4                // batches register-blocked per wave

// ---------------- LDS W staging (XOR-swizzled, double-buffered) --------
// Layout [j][n][m] f32 (16KB); byte ^= ((j&7)<<4) spreads the stride-512B
// j-column reads across bank groups (proven in R1).
__device__ __forceinline__ float4 ldsW(const float* base, int j, int byteInRow) {
  int byte = (j << 9) + byteInRow;
  byte ^= ((j & 7) << 4);
  return *(const float4*)((const char*)base + byte);
}

template <int TPB_>
__device__ __forceinline__ void stageW(float* dst, const float* src, int tid) {
#pragma unroll
  for (int q = 0; q < 1024 / TPB_; ++q) {      // 1024 float4 = 16KB
    int o = (tid + q * TPB_) << 4;
    int so = o ^ (((o >> 9) & 7) << 4);
    *(float4*)((char*)dst + so) = *(const float4*)((const char*)src + o);
  }
}

template <int TPB_, int IC_, bool ATOMIC>
__global__ __launch_bounds__(TPB_, 4) void caps_main(
    const float* __restrict__ u, const float* __restrict__ W,
    const float* __restrict__ bias, float* __restrict__ out, int nchunk) {
  __shared__ __align__(16) float wl[2][4096];
  constexpr int BPB_ = (TPB_ / 64) * BB;       // batches per block

  const int chunk = blockIdx.x;
  const int bg = blockIdx.y;
  const int tid = threadIdx.x;
  const int wid = tid >> 6;
  const int lane = tid & 63;
  const int j = lane >> 1;                     // parent capsule 0..31
  const int h = lane & 1;                      // m-octet
  const int b0 = __builtin_amdgcn_readfirstlane(bg * BPB_ + wid * BB);
  const int i0 = chunk * IC_;

  stageW<TPB_>(wl[0], W + (size_t)i0 * 4096, tid);

  float acc[BB][8];
#pragma unroll
  for (int bb = 0; bb < BB; ++bb)
#pragma unroll
    for (int k = 0; k < 8; ++k) acc[bb][k] = 0.f;

  for (int t = 0; t < IC_; ++t) {
    const int i = i0 + t;
    __syncthreads();  // wl[t&1] staged; all waves done reading wl[(t+1)&1]
    if (t + 1 < IC_) stageW<TPB_>(wl[(t + 1) & 1], W + (size_t)(i + 1) * 4096, tid);
    const float* wb = wl[t & 1];

    float un[BB][8];                           // wave-uniform -> scalar loads
#pragma unroll
    for (int bb = 0; bb < BB; ++bb) {
      const float* up = u + ((size_t)(b0 + bb) * NI + i) * 8;
      float4 a0 = *(const float4*)up;
      float4 a1 = *(const float4*)(up + 4);
      un[bb][0] = a0.x; un[bb][1] = a0.y; un[bb][2] = a0.z; un[bb][3] = a0.w;
      un[bb][4] = a1.x; un[bb][5] = a1.y; un[bb][6] = a1.z; un[bb][7] = a1.w;
    }
    const float bj = bias[(size_t)i * NJ + j];

    float uh[BB][8];
#pragma unroll
    for (int bb = 0; bb < BB; ++bb)
#pragma unroll
      for (int k = 0; k < 8; ++k) uh[bb][k] = 0.f;

#pragma unroll
    for (int n = 0; n < 8; ++n) {
      const int rb = n * 64 + h * 32;
      float4 w0 = ldsW(wb, j, rb);
      float4 w1 = ldsW(wb, j, rb + 16);
#pragma unroll
      for (int bb = 0; bb < BB; ++bb) {
        const float uv = un[bb][n];
        uh[bb][0] = fmaf(uv, w0.x, uh[bb][0]);
        uh[bb][1] = fmaf(uv, w0.y, uh[bb][1]);
        uh[bb][2] = fmaf(uv, w0.z, uh[bb][2]);
        uh[bb][3] = fmaf(uv, w0.w, uh[bb][3]);
        uh[bb][4] = fmaf(uv, w1.x, uh[bb][4]);
        uh[bb][5] = fmaf(uv, w1.y, uh[bb][5]);
        uh[bb][6] = fmaf(uv, w1.z, uh[bb][6]);
        uh[bb][7] = fmaf(uv, w1.w, uh[bb][7]);
      }
    }

    // agreement + MAX-FREE softmax over j (a = |uh|^2/4 is bounded ~[0,30];
    // exp is f32-safe without max subtraction) + bias.
    // lane = 2j+h: xor1 combines h-partners; xor2..xor32 sum over the 32 j.
#pragma unroll
    for (int bb = 0; bb < BB; ++bb) {
      float s2 = uh[bb][0] * uh[bb][0] + uh[bb][1] * uh[bb][1] +
                 uh[bb][2] * uh[bb][2] + uh[bb][3] * uh[bb][3] +
                 uh[bb][4] * uh[bb][4] + uh[bb][5] * uh[bb][5] +
                 uh[bb][6] * uh[bb][6] + uh[bb][7] * uh[bb][7];
      s2 += __shfl_xor(s2, 1);                 // full |u_hat|^2 (both octets)
      const float e = __expf(s2 * 0.25f);      // a = s2/sqrt(16); no max
      float es = e;
      es += __shfl_xor(es, 2);
      es += __shfl_xor(es, 4);
      es += __shfl_xor(es, 8);
      es += __shfl_xor(es, 16);
      es += __shfl_xor(es, 32);                // sum over all 32 j
      const float c = e * __builtin_amdgcn_rcpf(es) + bj;
#pragma unroll
      for (int k = 0; k < 8; ++k) acc[bb][k] = fmaf(c, uh[bb][k], acc[bb][k]);
    }
  }

#pragma unroll
  for (int bb = 0; bb < BB; ++bb) {
    if (ATOMIC) {
      float* p = out + (size_t)(b0 + bb) * JMSZ + j * DM + h * 8;
#pragma unroll
      for (int k = 0; k < 8; ++k) atomicAdd(p + k, acc[bb][k]);
    } else {
      float* p = out + ((size_t)(b0 + bb) * nchunk + chunk) * JMSZ + j * DM + h * 8;
      *(float4*)p = make_float4(acc[bb][0], acc[bb][1], acc[bb][2], acc[bb][3]);
      *(float4*)(p + 4) = make_float4(acc[bb][4], acc[bb][5], acc[bb][6], acc[bb][7]);
    }
  }
}

// Reduce chunk partials + squash. 4 threads per output element (q = gid&3
// each sums NSUM/4 chunks); q-combine and m-norm via __shfl_xor.
// lane bits: [1:0]=q, [5:2]=m (o = gid>>2, m = o&15).
template <int NSUM>
__global__ __launch_bounds__(256) void caps_fin(const float* __restrict__ part,
                                                float* __restrict__ v) {
  const int gid = blockIdx.x * 256 + threadIdx.x;
  const int o = gid >> 2;                      // output element b*512+j*16+m
  const int q = gid & 3;
  float s;
  if constexpr (NSUM == 1) {
    s = part[o];                               // q-lanes read same value
  } else {
    constexpr int QC = NSUM / 4;
    const int b = o >> 9;
    const int jm = o & 511;
    const float* p = part + (size_t)b * NSUM * JMSZ + (size_t)(q * QC) * JMSZ + jm;
    s = 0.f;
#pragma unroll
    for (int cc = 0; cc < QC; ++cc) s += p[(size_t)cc * JMSZ];
    s += __shfl_xor(s, 1);                     // combine q
    s += __shfl_xor(s, 2);
  }
  float sq = s * s;                            // s uniform in lane bits 0,1
  sq += __shfl_xor(sq, 4);                     // sum over m = lane bits 2-5
  sq += __shfl_xor(sq, 8);
  sq += __shfl_xor(sq, 16);
  sq += __shfl_xor(sq, 32);
  const float nrm = sqrtf(sq);
  const float f = (sq / (1.0f + sq)) / (nrm + 1e-20f);
  if (q == 0) v[o] = f * s;
}

extern "C" void kernel_launch(void* const* d_in, const int* in_sizes, int n_in,
                              void* d_out, int out_size, void* d_ws, size_t ws_size,
                              hipStream_t stream) {
  const float* u = (const float*)d_in[0];
  const float* W = (const float*)d_in[1];
  const float* bias = (const float*)d_in[2];
  float* out = (float*)d_out;

  const size_t P128 = (size_t)NB * 128 * JMSZ * sizeof(float);  // 32 MB
  const size_t P64 = (size_t)NB * 64 * JMSZ * sizeof(float);    // 16 MB
  const int finGrid = (NB * JMSZ * 4) / 256;                    // 1024

  if (ws_size >= P128) {
    // 1024 blocks of 256 thr -> 4 blocks/CU, 4 waves/SIMD
    float* part = (float*)d_ws;
    caps_main<256, 9, false><<<dim3(128, NB / 16), 256, 0, stream>>>(u, W, bias, part, 128);
    caps_fin<128><<<finGrid, 256, 0, stream>>>(part, out);
  } else if (ws_size >= P64) {
    // 512 blocks of 256 thr -> 2 blocks/CU
    float* part = (float*)d_ws;
    caps_main<256, 18, false><<<dim3(64, NB / 16), 256, 0, stream>>>(u, W, bias, part, 64);
    caps_fin<64><<<finGrid, 256, 0, stream>>>(part, out);
  } else {
    float* sbuf = (float*)d_ws;
    hipMemsetAsync(sbuf, 0, (size_t)NB * JMSZ * sizeof(float), stream);
    caps_main<256, 18, true><<<dim3(64, NB / 16), 256, 0, stream>>>(u, W, bias, sbuf, 64);
    caps_fin<1><<<finGrid, 256, 0, stream>>>(sbuf, out);
  }
}